// Round 8
// baseline (20.375 us; speedup 1.0000x reference)
//
#include <hip/hip_runtime.h>
#include <math.h>
#include <stdint.h>

#define NRAYS 8000
#define NB 2
#define GX 200
#define GY 200
#define GZ 16
#define BGRID (GX*GY*GZ)
#define NCH 18
#define FREE_ID 17
#define BLOCK 1024
#define RAYS_PER_BLOCK 64
#define NBLOCKS ((NB*NRAYS)/RAYS_PER_BLOCK)   // 250

// ---------------- host: replicate _ray_constants() exactly ----------------
namespace {

struct MT19937 {
  uint32_t mt[624]; int mti;
  void seed(uint32_t s){
    mt[0]=s;
    for (mti=1; mti<624; ++mti)
      mt[mti] = 1812433253u*(mt[mti-1]^(mt[mti-1]>>30)) + (uint32_t)mti;
  }
  uint32_t next(){
    if (mti >= 624){
      for (int i=0;i<624;i++){
        uint32_t y = (mt[i]&0x80000000u) | (mt[(i+1)%624]&0x7fffffffu);
        mt[i] = mt[(i+397)%624] ^ (y>>1) ^ ((y&1u)? 2567483615u : 0u);
      }
      mti = 0;
    }
    uint32_t y = mt[mti++];
    y ^= y>>11; y ^= (y<<7)&2636928640u; y ^= (y<<15)&4022730752u; y ^= y>>18;
    return y;
  }
};

static uint32_t rinterval(MT19937& g, uint32_t mx){
  if (mx==0) return 0;
  uint32_t mask=mx; mask|=mask>>1; mask|=mask>>2; mask|=mask>>4; mask|=mask>>8; mask|=mask>>16;
  uint32_t v;
  do { v = g.next()&mask; } while (v>mx);
  return v;
}

static int build_table(float4* out){
  double pitch[128]; int npi=0;
  for (int k=0;k<10;k++) pitch[npi++] = -(M_PI/2.0 - atan((double)(k+1)));
  while (pitch[npi-1] < 0.21){
    double d = pitch[npi-1]-pitch[npi-2];
    pitch[npi] = pitch[npi-1]+d; ++npi;
  }
  int nrays = npi*360;   // 39*360 = 14040
  static float rx[128*360], ry[128*360], rz[128*360], rdt[128*360];
  float dtmin = 1e30f;
  for (int p=0;p<npi;p++){
    double cp = cos(pitch[p]), sp = sin(pitch[p]);
    for (int a=0;a<360;a++){
      double az = (double)a * (M_PI/180.0);
      int i = p*360+a;
      rx[i]=(float)(cp*cos(az)); ry[i]=(float)(cp*sin(az)); rz[i]=(float)sp;
      float ma = fmaxf(fabsf(rx[i]), fmaxf(fabsf(ry[i]), fabsf(rz[i])));
      ma = ma + 1e-8f;
      rdt[i] = 0.4f/ma;
      if (rdt[i] < dtmin) dtmin = rdt[i];
    }
  }
  int smax = (int)fmin(ceil(60.0/(double)dtmin), 512.0);
  static int perm[128*360];
  for (int i=0;i<nrays;i++) perm[i]=i;
  MT19937 g; g.seed(0);
  for (int i=nrays-1;i>=1;--i){
    uint32_t j = rinterval(g, (uint32_t)i);
    int tmp = perm[i]; perm[i]=perm[j]; perm[j]=tmp;
  }
  for (int i=0;i<NRAYS;i++){
    int id = perm[i];
    out[i] = make_float4(rx[id], ry[id], rz[id], rdt[id]);
  }
  return smax;
}

// Built once at library load (input-independent constant, like the reference's
// module-level _DIRS/_DT). Device copy allocated+filled OUTSIDE kernel_launch
// and outside graph capture, so the graph needs no H2D node.
struct TabHolder {
  float4* h;        // pinned (or pageable fallback) host copy
  float4* d;        // persistent device copy (null -> fallback path)
  int smax;
  TabHolder(){
    h = nullptr; d = nullptr;
    if (hipHostMalloc((void**)&h, sizeof(float4)*NRAYS, 0) != hipSuccess || !h){
      static float4 fb[NRAYS]; h = fb;
    }
    smax = build_table(h);
    float4* dp = nullptr;
    if (hipMalloc((void**)&dp, sizeof(float4)*NRAYS) == hipSuccess && dp){
      if (hipMemcpy(dp, h, sizeof(float4)*NRAYS, hipMemcpyHostToDevice) == hipSuccess)
        d = dp;
    }
  }
};
static TabHolder g_tab;

} // namespace

// ---------------- device ----------------

// step geometry; separately-rounded mul/add/div to match the reference exactly
__device__ inline void probe(float ox,float oy,float oz,const float4& rd,
                             int s,int S,int& flat,bool& tok,bool& inb)
{
  float t = __fmul_rn(rd.w, (float)s + 0.5f);
  tok = (s < S) && (t <= 60.0f);
  float px = __fadd_rn(ox, __fmul_rn(rd.x, t));
  float py = __fadd_rn(oy, __fmul_rn(rd.y, t));
  float pz = __fadd_rn(oz, __fmul_rn(rd.z, t));
  int vx = (int)floorf(__fdiv_rn(__fadd_rn(px, 40.0f), 0.4f));
  int vy = (int)floorf(__fdiv_rn(__fadd_rn(py, 40.0f), 0.4f));
  int vz = (int)floorf(__fdiv_rn(__fadd_rn(pz, 1.0f), 0.4f));
  flat = (vx*GY+vy)*GZ+vz;
  inb = tok & ((unsigned)vx < (unsigned)GX) & ((unsigned)vy < (unsigned)GY)
            & ((unsigned)vz < (unsigned)GZ);
}

__device__ inline void lse18(const float* __restrict__ lg, float& mx, float& ls){
  float m = lg[0];
  #pragma unroll
  for (int c=1;c<NCH;c++) m = fmaxf(m, lg[c]);
  float s = 0.f;
  #pragma unroll
  for (int c=0;c<NCH;c++) s += expf(lg[c]-m);
  mx = m; ls = logf(s);
}

// 16 lanes per ray (4 rays/wave). Scan rounds carry ONLY probe + sem/cam
// gather + ballot (minimal dependent chain); the pre-hit BCE (logits gather
// + 18-wide log-softmax) runs in a post-pass restricted to camera-valid rays
// (half of rays are invalid -> their lse18 work was pure waste in R7).
__global__ __launch_bounds__(BLOCK) void ray_loss_kernel(
    const float* __restrict__ logits, const float* __restrict__ origins,
    const int* __restrict__ sem, const int* __restrict__ cam,
    const float4* __restrict__ rays, float* __restrict__ partials, int S)
{
  const int wv = threadIdx.x >> 6, lane = threadIdx.x & 63;
  const int gi = lane >> 4;                 // group (ray) within wave, 0..3
  const int gl = lane & 15;                 // lane within group
  const int g0 = gi << 4;
  const unsigned long long gmask = 0xFFFFULL << g0;

  const int ray = blockIdx.x*RAYS_PER_BLOCK + wv*4 + gi;   // 0..15999
  const int b = (ray >= NRAYS) ? 1 : 0;     // block-uniform (8000 = 125*64)
  const int r = ray - b*NRAYS;
  const float ox=origins[b*3+0], oy=origins[b*3+1], oz=origins[b*3+2];
  const float4 rd = rays[r];
  const int* semb = sem + b*BGRID;
  const int* camb = cam + b*BGRID;

  // ---- phase 1: minimal scan rounds (no logits work on this path) ----
  bool resolved = false, entered = false;
  int hit = -1, hflat = 0, hgt = 0, hcam = 0;
  for (int R=0; (R<<4) < S; ++R){
    if (__ballot(!resolved) == 0ULL) break;
    if (!resolved){
      const int s = (R<<4) + gl;
      int fl; bool tok, inb;
      probe(ox,oy,oz,rd,s,S,fl,tok,inb);
      const int a = inb ? fl : 0;
      const int gt = semb[a];               // sem + cam in the SAME round
      const int cm = camb[a];
      const unsigned long long occ  = __ballot(inb && (gt != FREE_ID)) & gmask;
      const unsigned long long binb = __ballot(inb);
      const unsigned long long btok = __ballot(tok);
      if (occ){
        const int f = __ffsll(occ) - 1;     // absolute lane of first hit
        hit   = (R<<4) + (f - g0);
        hflat = __shfl(fl, f);
        hgt   = __shfl(gt, f);
        hcam  = __shfl(cm, f);
        resolved = true;
      } else {
        entered |= (binb & gmask) != 0ULL;
        const bool g_last_inb = (binb >> (g0+15)) & 1ULL;
        const bool g_last_tok = (btok >> (g0+15)) & 1ULL;
        // convex box: once entered then out -> never in-bounds again
        if (!g_last_tok || (entered && !g_last_inb)) resolved = true; // no hit
      }
    }
  }

  const bool rv = (hit >= 0) && (hcam > 0);

  // ---- phase 2: pre-hit free-space BCE, valid rays only ----
  float npre = 0.f, spre = 0.f;
  if (rv){
    for (int s = gl; s < hit; s += 16){     // typically 0-2 total steps/ray
      int fl; bool tok, inb;
      probe(ox,oy,oz,rd,s,S,fl,tok,inb);
      if (inb){
        const float* lg2 = logits + (size_t)(b*BGRID+fl)*NCH;
        float mx2, ls2; lse18(lg2, mx2, ls2);
        spre += -logf(fmaxf(expf((lg2[FREE_ID]-mx2) - ls2), 1e-6f));
        npre += 1.f;
      }
    }
  }
  #pragma unroll
  for (int off=1; off<16; off<<=1){         // group reduce (stays in 16-group)
    npre += __shfl_xor(npre, off);
    spre += __shfl_xor(spre, off);
  }

  float v0=0.f, v1=0.f, v2=0.f, v3=0.f, v4=0.f;
  if (gl == 0 && rv){                       // hit terms, one lane per group
    const float* lg = logits + (size_t)(b*BGRID+hflat)*NCH;
    float mx, ls; lse18(lg, mx, ls);
    float pf = expf((lg[FREE_ID]-mx) - ls);
    v0 = npre; v1 = spre; v2 = 1.f;
    v3 = -logf(fmaxf(1.0f - pf, 1e-6f));
    v4 = -((lg[hgt]-mx) - ls);
  }
  // wave combine: sum the 4 group leaders (lanes 0,16,32,48)
  v0 = __shfl(v0,0)+__shfl(v0,16)+__shfl(v0,32)+__shfl(v0,48);
  v1 = __shfl(v1,0)+__shfl(v1,16)+__shfl(v1,32)+__shfl(v1,48);
  v2 = __shfl(v2,0)+__shfl(v2,16)+__shfl(v2,32)+__shfl(v2,48);
  v3 = __shfl(v3,0)+__shfl(v3,16)+__shfl(v3,32)+__shfl(v3,48);
  v4 = __shfl(v4,0)+__shfl(v4,16)+__shfl(v4,32)+__shfl(v4,48);

  __shared__ float red[BLOCK/64][5];
  if (lane == 0){
    red[wv][0]=v0; red[wv][1]=v1; red[wv][2]=v2; red[wv][3]=v3; red[wv][4]=v4;
  }
  __syncthreads();
  // publish full 10-wide row (other batch's half = 0) with plain stores;
  // kernel boundary is the release/acquire (no fences — R3/R4 lesson).
  if (wv == 0 && lane < 10){
    const int jj = lane - b*5;
    float s = 0.f;
    if (jj >= 0 && jj < 5){
      #pragma unroll
      for (int k=0;k<BLOCK/64;k++) s += red[k][jj];
    }
    partials[(size_t)blockIdx.x*10 + lane] = s;
  }
}

__global__ __launch_bounds__(64) void finalize_kernel(
    const float* __restrict__ partials, float* __restrict__ out, int nblocks)
{
  double a[10];
  #pragma unroll
  for (int j=0;j<10;j++) a[j]=0.0;
  for (int r = threadIdx.x; r < nblocks; r += 64){
    #pragma unroll
    for (int j=0;j<10;j++) a[j] += (double)partials[(size_t)r*10+j];
  }
  #pragma unroll
  for (int j=0;j<10;j++){
    for (int off=32; off>=1; off>>=1) a[j] += __shfl_down(a[j], off);
  }
  if (threadIdx.x==0){
    double sp=0, cp=0, sh=0, sc=0, ch=0;
    for (int b=0;b<NB;b++){
      double n_pre=a[b*5+0], s_pre=a[b*5+1];
      double n_ray=a[b*5+2], s_hit=a[b*5+3], s_ce=a[b*5+4];
      if (n_pre>0.0){ sp += s_pre/n_pre; cp+=1.0; }
      if (n_ray>0.0){ sh += s_hit/n_ray; sc += s_ce/n_ray; ch+=1.0; }
    }
    double lp = sp / (cp>0.0?cp:1.0);
    double lh = sh / (ch>0.0?ch:1.0);
    double lc = sc / (ch>0.0?ch:1.0);
    out[0] = (float)(lp+lh+lc);
  }
}

extern "C" void kernel_launch(void* const* d_in, const int* in_sizes, int n_in,
                              void* d_out, int out_size, void* d_ws, size_t ws_size,
                              hipStream_t stream)
{
  (void)in_sizes; (void)n_in; (void)out_size; (void)ws_size;
  const float* logits  = (const float*)d_in[0];
  const float* origins = (const float*)d_in[1];
  const int*   sem     = (const int*)d_in[2];
  const int*   cam     = (const int*)d_in[3];
  float* out = (float*)d_out;

  // d_ws layout: [0..10kB) partials (250*10 f32, fully overwritten every call
  // by all 250 blocks), [64kB..) fallback ray-table slot.
  float* partials = (float*)d_ws;

  const float4* d_tab = g_tab.d;
  if (!d_tab){   // constructor alloc failed: fall back to per-call H2D copy
    float4* slot = (float4*)((char*)d_ws + 65536);
    hipMemcpyAsync(slot, g_tab.h, sizeof(float4)*NRAYS,
                   hipMemcpyHostToDevice, stream);
    d_tab = slot;
  }

  ray_loss_kernel<<<NBLOCKS, BLOCK, 0, stream>>>(logits, origins, sem, cam,
                                                 d_tab, partials, g_tab.smax);
  finalize_kernel<<<1, 64, 0, stream>>>(partials, out, NBLOCKS);
}

// Round 9
// 16.143 us; speedup vs baseline: 1.2621x; 1.2621x over previous
//
#include <hip/hip_runtime.h>
#include <math.h>
#include <stdint.h>

#define NRAYS 8000
#define NB 2
#define GX 200
#define GY 200
#define GZ 16
#define BGRID (GX*GY*GZ)
#define NCH 18
#define FREE_ID 17
#define BLOCK 1024
#define RAYS_PER_BLOCK 64
#define NBLOCKS ((NB*NRAYS)/RAYS_PER_BLOCK)   // 250

// ---------------- host: replicate _ray_constants() exactly ----------------
namespace {

struct MT19937 {
  uint32_t mt[624]; int mti;
  void seed(uint32_t s){
    mt[0]=s;
    for (mti=1; mti<624; ++mti)
      mt[mti] = 1812433253u*(mt[mti-1]^(mt[mti-1]>>30)) + (uint32_t)mti;
  }
  uint32_t next(){
    if (mti >= 624){
      for (int i=0;i<624;i++){
        uint32_t y = (mt[i]&0x80000000u) | (mt[(i+1)%624]&0x7fffffffu);
        mt[i] = mt[(i+397)%624] ^ (y>>1) ^ ((y&1u)? 2567483615u : 0u);
      }
      mti = 0;
    }
    uint32_t y = mt[mti++];
    y ^= y>>11; y ^= (y<<7)&2636928640u; y ^= (y<<15)&4022730752u; y ^= y>>18;
    return y;
  }
};

static uint32_t rinterval(MT19937& g, uint32_t mx){
  if (mx==0) return 0;
  uint32_t mask=mx; mask|=mask>>1; mask|=mask>>2; mask|=mask>>4; mask|=mask>>8; mask|=mask>>16;
  uint32_t v;
  do { v = g.next()&mask; } while (v>mx);
  return v;
}

static int build_table(float4* out){
  double pitch[128]; int npi=0;
  for (int k=0;k<10;k++) pitch[npi++] = -(M_PI/2.0 - atan((double)(k+1)));
  while (pitch[npi-1] < 0.21){
    double d = pitch[npi-1]-pitch[npi-2];
    pitch[npi] = pitch[npi-1]+d; ++npi;
  }
  int nrays = npi*360;   // 39*360 = 14040
  static float rx[128*360], ry[128*360], rz[128*360], rdt[128*360];
  float dtmin = 1e30f;
  for (int p=0;p<npi;p++){
    double cp = cos(pitch[p]), sp = sin(pitch[p]);
    for (int a=0;a<360;a++){
      double az = (double)a * (M_PI/180.0);
      int i = p*360+a;
      rx[i]=(float)(cp*cos(az)); ry[i]=(float)(cp*sin(az)); rz[i]=(float)sp;
      float ma = fmaxf(fabsf(rx[i]), fmaxf(fabsf(ry[i]), fabsf(rz[i])));
      ma = ma + 1e-8f;
      rdt[i] = 0.4f/ma;
      if (rdt[i] < dtmin) dtmin = rdt[i];
    }
  }
  int smax = (int)fmin(ceil(60.0/(double)dtmin), 512.0);
  static int perm[128*360];
  for (int i=0;i<nrays;i++) perm[i]=i;
  MT19937 g; g.seed(0);
  for (int i=nrays-1;i>=1;--i){
    uint32_t j = rinterval(g, (uint32_t)i);
    int tmp = perm[i]; perm[i]=perm[j]; perm[j]=tmp;
  }
  for (int i=0;i<NRAYS;i++){
    int id = perm[i];
    out[i] = make_float4(rx[id], ry[id], rz[id], rdt[id]);
  }
  return smax;
}

// Built once at library load (input-independent constant, like the reference's
// module-level _DIRS/_DT). Device copy allocated+filled OUTSIDE kernel_launch
// and outside graph capture, so the graph needs no H2D node.
struct TabHolder {
  float4* h;        // pinned (or pageable fallback) host copy
  float4* d;        // persistent device copy (null -> fallback path)
  int smax;
  TabHolder(){
    h = nullptr; d = nullptr;
    if (hipHostMalloc((void**)&h, sizeof(float4)*NRAYS, 0) != hipSuccess || !h){
      static float4 fb[NRAYS]; h = fb;
    }
    smax = build_table(h);
    float4* dp = nullptr;
    if (hipMalloc((void**)&dp, sizeof(float4)*NRAYS) == hipSuccess && dp){
      if (hipMemcpy(dp, h, sizeof(float4)*NRAYS, hipMemcpyHostToDevice) == hipSuccess)
        d = dp;
    }
  }
};
static TabHolder g_tab;

} // namespace

// ---------------- device ----------------

// step geometry; separately-rounded mul/add/div to match the reference exactly
__device__ inline void probe(float ox,float oy,float oz,const float4& rd,
                             int s,int S,int& flat,bool& tok,bool& inb)
{
  float t = __fmul_rn(rd.w, (float)s + 0.5f);
  tok = (s < S) && (t <= 60.0f);
  float px = __fadd_rn(ox, __fmul_rn(rd.x, t));
  float py = __fadd_rn(oy, __fmul_rn(rd.y, t));
  float pz = __fadd_rn(oz, __fmul_rn(rd.z, t));
  int vx = (int)floorf(__fdiv_rn(__fadd_rn(px, 40.0f), 0.4f));
  int vy = (int)floorf(__fdiv_rn(__fadd_rn(py, 40.0f), 0.4f));
  int vz = (int)floorf(__fdiv_rn(__fadd_rn(pz, 1.0f), 0.4f));
  flat = (vx*GY+vy)*GZ+vz;
  inb = tok & ((unsigned)vx < (unsigned)GX) & ((unsigned)vy < (unsigned)GY)
            & ((unsigned)vz < (unsigned)GZ);
}

__device__ inline void lse18(const float* __restrict__ lg, float& mx, float& ls){
  float m = lg[0];
  #pragma unroll
  for (int c=1;c<NCH;c++) m = fmaxf(m, lg[c]);
  float s = 0.f;
  #pragma unroll
  for (int c=0;c<NCH;c++) s += expf(lg[c]-m);
  mx = m; ls = logf(s);
}

// 16 lanes per ray (4 rays/wave). The scan is clamped to a conservative
// analytic box-crossing interval (slab test, ±2-step margin): never-entering
// rays do ZERO gather rounds (they were the 10-round slowest-wave tail),
// late-entering rays skip their leading out-of-bounds rounds. The exact
// per-step probe still decides membership — the clamp only bounds the range.
__global__ __launch_bounds__(BLOCK) void ray_loss_kernel(
    const float* __restrict__ logits, const float* __restrict__ origins,
    const int* __restrict__ sem, const int* __restrict__ cam,
    const float4* __restrict__ rays, float* __restrict__ partials, int S)
{
  const int wv = threadIdx.x >> 6, lane = threadIdx.x & 63;
  const int gi = lane >> 4;                 // group (ray) within wave, 0..3
  const int gl = lane & 15;                 // lane within group
  const int g0 = gi << 4;
  const unsigned long long gmask = 0xFFFFULL << g0;

  const int ray = blockIdx.x*RAYS_PER_BLOCK + wv*4 + gi;   // 0..15999
  const int b = (ray >= NRAYS) ? 1 : 0;     // block-uniform (8000 = 125*64)
  const int r = ray - b*NRAYS;
  const float ox=origins[b*3+0], oy=origins[b*3+1], oz=origins[b*3+2];
  const float4 rd = rays[r];
  const int* semb = sem + b*BGRID;
  const int* camb = cam + b*BGRID;

  // ---- analytic conservative scan range (group-uniform) ----
  int s_lo = 0, nrounds = 0;
  {
    float tent = 0.f, texi = 60.0f;
    bool empty = false;
    const float lo[3] = {-40.f, -40.f, -1.f};
    const float hi[3] = { 40.f,  40.f,  5.4f};   // PC_MIN + GRID*0.4
    const float oo[3] = {ox, oy, oz};
    const float dd[3] = {rd.x, rd.y, rd.z};
    #pragma unroll
    for (int a2=0;a2<3;a2++){
      if (fabsf(dd[a2]) < 1e-8f){
        if (oo[a2] < lo[a2] || oo[a2] >= hi[a2]) empty = true;
      } else {
        float t0 = (lo[a2]-oo[a2])/dd[a2];
        float t1 = (hi[a2]-oo[a2])/dd[a2];
        tent = fmaxf(tent, fminf(t0,t1));
        texi = fminf(texi, fmaxf(t0,t1));
      }
    }
    if (!empty && tent <= texi){
      s_lo = (int)floorf(tent/rd.w - 0.5f) - 2;
      if (s_lo < 0) s_lo = 0;
      int s_hi = (int)ceilf(texi/rd.w) + 2;       // probe's tok/inb still filter
      if (s_hi > S-1) s_hi = S-1;
      if (s_hi >= s_lo) nrounds = ((s_hi - s_lo) >> 4) + 1;
    }
  }

  // ---- phase 1: minimal scan rounds (probe + sem/cam gather + ballot) ----
  bool resolved = (nrounds == 0), entered = false;
  int hit = -1, hflat = 0, hgt = 0, hcam = 0;
  for (int i=0; ; ++i){
    if (__ballot(!resolved) == 0ULL) break;
    if (!resolved){
      if (i >= nrounds){ resolved = true; }       // range exhausted: no hit
      else {
        const int s = s_lo + (i<<4) + gl;
        int fl; bool tok, inb;
        probe(ox,oy,oz,rd,s,S,fl,tok,inb);
        const int a = inb ? fl : 0;
        const int gt = semb[a];                   // sem + cam in the SAME round
        const int cm = camb[a];
        const unsigned long long occ  = __ballot(inb && (gt != FREE_ID)) & gmask;
        const unsigned long long binb = __ballot(inb);
        const unsigned long long btok = __ballot(tok);
        if (occ){
          const int f = __ffsll(occ) - 1;         // absolute lane of first hit
          hit   = s_lo + (i<<4) + (f - g0);
          hflat = __shfl(fl, f);
          hgt   = __shfl(gt, f);
          hcam  = __shfl(cm, f);
          resolved = true;
        } else {
          entered |= (binb & gmask) != 0ULL;
          const bool g_last_inb = (binb >> (g0+15)) & 1ULL;
          const bool g_last_tok = (btok >> (g0+15)) & 1ULL;
          // convex box: once entered then out -> never in-bounds again
          if (!g_last_tok || (entered && !g_last_inb)) resolved = true; // no hit
        }
      }
    }
  }

  const bool rv = (hit >= 0) && (hcam > 0);

  // ---- phase 2: pre-hit free-space BCE, valid rays only ----
  float npre = 0.f, spre = 0.f;
  if (rv){
    for (int s = gl; s < hit; s += 16){     // typically 0-2 total steps/ray
      int fl; bool tok, inb;
      probe(ox,oy,oz,rd,s,S,fl,tok,inb);
      if (inb){
        const float* lg2 = logits + (size_t)(b*BGRID+fl)*NCH;
        float mx2, ls2; lse18(lg2, mx2, ls2);
        spre += -logf(fmaxf(expf((lg2[FREE_ID]-mx2) - ls2), 1e-6f));
        npre += 1.f;
      }
    }
  }
  #pragma unroll
  for (int off=1; off<16; off<<=1){         // group reduce (stays in 16-group)
    npre += __shfl_xor(npre, off);
    spre += __shfl_xor(spre, off);
  }

  float v0=0.f, v1=0.f, v2=0.f, v3=0.f, v4=0.f;
  if (gl == 0 && rv){                       // hit terms, one lane per group
    const float* lg = logits + (size_t)(b*BGRID+hflat)*NCH;
    float mx, ls; lse18(lg, mx, ls);
    float pf = expf((lg[FREE_ID]-mx) - ls);
    v0 = npre; v1 = spre; v2 = 1.f;
    v3 = -logf(fmaxf(1.0f - pf, 1e-6f));
    v4 = -((lg[hgt]-mx) - ls);
  }
  // wave combine: sum the 4 group leaders (lanes 0,16,32,48)
  v0 = __shfl(v0,0)+__shfl(v0,16)+__shfl(v0,32)+__shfl(v0,48);
  v1 = __shfl(v1,0)+__shfl(v1,16)+__shfl(v1,32)+__shfl(v1,48);
  v2 = __shfl(v2,0)+__shfl(v2,16)+__shfl(v2,32)+__shfl(v2,48);
  v3 = __shfl(v3,0)+__shfl(v3,16)+__shfl(v3,32)+__shfl(v3,48);
  v4 = __shfl(v4,0)+__shfl(v4,16)+__shfl(v4,32)+__shfl(v4,48);

  __shared__ float red[BLOCK/64][5];
  if (lane == 0){
    red[wv][0]=v0; red[wv][1]=v1; red[wv][2]=v2; red[wv][3]=v3; red[wv][4]=v4;
  }
  __syncthreads();
  // publish full 10-wide row (other batch's half = 0) with plain stores;
  // kernel boundary is the release/acquire (no fences — R3/R4 lesson).
  if (wv == 0 && lane < 10){
    const int jj = lane - b*5;
    float s = 0.f;
    if (jj >= 0 && jj < 5){
      #pragma unroll
      for (int k=0;k<BLOCK/64;k++) s += red[k][jj];
    }
    partials[(size_t)blockIdx.x*10 + lane] = s;
  }
}

__global__ __launch_bounds__(64) void finalize_kernel(
    const float* __restrict__ partials, float* __restrict__ out, int nblocks)
{
  double a[10];
  #pragma unroll
  for (int j=0;j<10;j++) a[j]=0.0;
  for (int r = threadIdx.x; r < nblocks; r += 64){
    #pragma unroll
    for (int j=0;j<10;j++) a[j] += (double)partials[(size_t)r*10+j];
  }
  #pragma unroll
  for (int j=0;j<10;j++){
    for (int off=32; off>=1; off>>=1) a[j] += __shfl_down(a[j], off);
  }
  if (threadIdx.x==0){
    double sp=0, cp=0, sh=0, sc=0, ch=0;
    for (int b=0;b<NB;b++){
      double n_pre=a[b*5+0], s_pre=a[b*5+1];
      double n_ray=a[b*5+2], s_hit=a[b*5+3], s_ce=a[b*5+4];
      if (n_pre>0.0){ sp += s_pre/n_pre; cp+=1.0; }
      if (n_ray>0.0){ sh += s_hit/n_ray; sc += s_ce/n_ray; ch+=1.0; }
    }
    double lp = sp / (cp>0.0?cp:1.0);
    double lh = sh / (ch>0.0?ch:1.0);
    double lc = sc / (ch>0.0?ch:1.0);
    out[0] = (float)(lp+lh+lc);
  }
}

extern "C" void kernel_launch(void* const* d_in, const int* in_sizes, int n_in,
                              void* d_out, int out_size, void* d_ws, size_t ws_size,
                              hipStream_t stream)
{
  (void)in_sizes; (void)n_in; (void)out_size; (void)ws_size;
  const float* logits  = (const float*)d_in[0];
  const float* origins = (const float*)d_in[1];
  const int*   sem     = (const int*)d_in[2];
  const int*   cam     = (const int*)d_in[3];
  float* out = (float*)d_out;

  // d_ws layout: [0..10kB) partials (250*10 f32, fully overwritten every call
  // by all 250 blocks), [64kB..) fallback ray-table slot.
  float* partials = (float*)d_ws;

  const float4* d_tab = g_tab.d;
  if (!d_tab){   // constructor alloc failed: fall back to per-call H2D copy
    float4* slot = (float4*)((char*)d_ws + 65536);
    hipMemcpyAsync(slot, g_tab.h, sizeof(float4)*NRAYS,
                   hipMemcpyHostToDevice, stream);
    d_tab = slot;
  }

  ray_loss_kernel<<<NBLOCKS, BLOCK, 0, stream>>>(logits, origins, sem, cam,
                                                 d_tab, partials, g_tab.smax);
  finalize_kernel<<<1, 64, 0, stream>>>(partials, out, NBLOCKS);
}